// Round 5
// baseline (849.716 us; speedup 1.0000x reference)
//
#include <hip/hip_runtime.h>
#include <hip/hip_bf16.h>

#define F 128

typedef __attribute__((ext_vector_type(8))) short short8;    // 8 bf16 = 4 VGPRs
typedef __attribute__((ext_vector_type(4))) float floatx4;   // MFMA C/D

__device__ __forceinline__ float bf_lo(unsigned u) { return __uint_as_float(u << 16); }
__device__ __forceinline__ float bf_hi(unsigned u) { return __uint_as_float(u & 0xffff0000u); }

// fp32 -> bf16 bits, round-to-nearest-even
__device__ __forceinline__ unsigned short f2bf(float x) {
  unsigned u = __float_as_uint(x);
  u += 0x7fffu + ((u >> 16) & 1u);
  return (unsigned short)(u >> 16);
}

// -------- CSR build step 1: histogram of dst --------
__global__ __launch_bounds__(256) void k_count(const int* __restrict__ dst,
                                               int* __restrict__ A, int E) {
  int e = blockIdx.x * 256 + threadIdx.x;
  if (e < E) atomicAdd(&A[dst[e]], 1);
}

// -------- CSR build step 2: in-place exclusive scan (single 1024-thread block) --------
__global__ __launch_bounds__(1024) void k_scan(int* __restrict__ A, int n) {
  __shared__ int wtot[16];
  int t = threadIdx.x, l = t & 63, w = t >> 6;
  int base = 0;
  for (int i0 = 0; i0 < n; i0 += 1024) {
    int i = i0 + t;
    int v = (i < n) ? A[i] : 0;
    int acc = v;
#pragma unroll
    for (int off = 1; off < 64; off <<= 1) {
      int u = __shfl_up(acc, off);
      if (l >= off) acc += u;
    }
    if (l == 63) wtot[w] = acc;
    __syncthreads();
    int woff = 0, total = 0;
#pragma unroll
    for (int ww = 0; ww < 16; ++ww) {
      total += wtot[ww];
      if (ww < w) woff += wtot[ww];
    }
    if (i < n) A[i] = base + woff + (acc - v);
    base += total;
    __syncthreads();
  }
}

// -------- CSR build step 3: fill adjacency; A becomes row-end (inclusive) --------
__global__ __launch_bounds__(256) void k_fill(const int* __restrict__ srcT,
                                              const int* __restrict__ dst,
                                              int* __restrict__ A, int* __restrict__ adj, int E) {
  int e = blockIdx.x * 256 + threadIdx.x;
  if (e >= E) return;
  int s = srcT[e], d = dst[e];
  int slot = atomicAdd(&A[d], 1);
  adj[slot] = s;
}

// -------- weight prep: WcatT[n][k] bf16, k in [0,256) = [Wl ; Wr] --------
__global__ __launch_bounds__(256) void k_prepw(const float* __restrict__ Wl,
                                               const float* __restrict__ Wr,
                                               unsigned short* __restrict__ WcatT) {
  int i = blockIdx.x * 256 + threadIdx.x;
  if (i >= 256 * F) return;
  int k = i >> 7, n = i & (F - 1);
  float v = (k < F) ? Wl[k * F + n] : Wr[(k - F) * F + n];
  WcatT[(size_t)n * 256 + k] = f2bf(v);
}

// -------- fp32 -> bf16 convert (x -> xb) --------
__global__ __launch_bounds__(256) void k_cvt(const float* __restrict__ x,
                                             unsigned short* __restrict__ xb, int n4) {
  int i = blockIdx.x * 256 + threadIdx.x;
  if (i >= n4) return;
  float4 v = ((const float4*)x)[i];
  ushort4 o = make_ushort4(f2bf(v.x), f2bf(v.y), f2bf(v.z), f2bf(v.w));
  ((ushort4*)xb)[i] = o;
}

// -------- mean aggregation by gather: one wave per dst row; bf16 in/out --------
__global__ __launch_bounds__(256) void k_gather(const unsigned short* __restrict__ xin,
                                                const int* __restrict__ A,
                                                const int* __restrict__ adj,
                                                unsigned short* __restrict__ aggb, int N) {
  int d = blockIdx.x * 4 + (threadIdx.x >> 6);
  if (d >= N) return;
  int l = threadIdx.x & 63;
  int e0 = (d == 0) ? 0 : A[d - 1];
  int e1 = A[d];
  int deg = e1 - e0;
  float2 acc = make_float2(0.f, 0.f);
  int ids = (e0 + l < e1) ? adj[e0 + l] : 0;
  int m = min(deg, 64);
  for (int j = 0; j < m; ++j) {
    int s = __shfl(ids, j);
    unsigned u = ((const unsigned*)xin)[(size_t)s * 64 + l];
    acc.x += bf_lo(u);
    acc.y += bf_hi(u);
  }
  for (int e = e0 + 64; e < e1; ++e) {
    int s = adj[e];
    unsigned u = ((const unsigned*)xin)[(size_t)s * 64 + l];
    acc.x += bf_lo(u);
    acc.y += bf_hi(u);
  }
  float inv = 1.0f / fmaxf((float)deg, 1.0f);
  unsigned out = (unsigned)f2bf(acc.x * inv) | ((unsigned)f2bf(acc.y * inv) << 16);
  ((unsigned*)aggb)[(size_t)d * 64 + l] = out;
}

// -------- MFMA gemm: h[N][128] = [aggb | xb] @ Wcat + bias, + BN stats --------
// 4 waves/block; wave w owns cols [32w, 32w+32). B fragments in registers
// (WcatT is [n][k] so each fragment is one 16-B vector load).
// __launch_bounds__(256,1): ~160 live VGPRs needed; R4's default cap (88) spilled
// B-fragments to scratch -> 99% stall. Do NOT tighten this bound.
__global__ __launch_bounds__(256, 1) void k_gemm(
    const unsigned short* __restrict__ aggb, const unsigned short* __restrict__ xb,
    const unsigned short* __restrict__ WcatT, const float* __restrict__ bias,
    float* __restrict__ hout, float* __restrict__ csum, float* __restrict__ csumsq,
    int N, int nRowBlocks) {
  const int w = threadIdx.x >> 6;
  const int l = threadIdx.x & 63;
  const int lm = l & 15;   // tile row (A) / tile col (B, C/D)
  const int lq = l >> 4;   // quad
  const int cbase = 32 * w;

  // B fragments: [ctile][kstep]; lane holds B[k = 32s + 8*lq + j][n = cbase + 16c + lm]
  short8 bfrag[2][8];
#pragma unroll
  for (int c = 0; c < 2; ++c) {
    int col = cbase + 16 * c + lm;
    const unsigned short* wp = WcatT + (size_t)col * 256 + lq * 8;
#pragma unroll
    for (int s = 0; s < 8; ++s) bfrag[c][s] = *(const short8*)(wp + 32 * s);
  }
  float bcol0 = bias[cbase + lm];
  float bcol1 = bias[cbase + 16 + lm];
  float bsum0 = 0.f, bsum1 = 0.f, bsq0 = 0.f, bsq1 = 0.f;

  for (int rb = blockIdx.x; rb < nRowBlocks; rb += gridDim.x) {
    int r0 = rb * 64;
    floatx4 acc[4][2] = {};
#pragma unroll
    for (int t = 0; t < 4; ++t) {
      int r = r0 + 16 * t + lm;  // pad rows exist; stores guarded
      const unsigned short* arow = aggb + (size_t)r * F + lq * 8;
      const unsigned short* xrow = xb + (size_t)r * F + lq * 8;
      short8 af[8];
#pragma unroll
      for (int s = 0; s < 4; ++s) {
        af[s] = *(const short8*)(arow + 32 * s);
        af[s + 4] = *(const short8*)(xrow + 32 * s);
      }
#pragma unroll
      for (int s = 0; s < 8; ++s) {
        acc[t][0] = __builtin_amdgcn_mfma_f32_16x16x32_bf16(af[s], bfrag[0][s], acc[t][0], 0, 0, 0);
        acc[t][1] = __builtin_amdgcn_mfma_f32_16x16x32_bf16(af[s], bfrag[1][s], acc[t][1], 0, 0, 0);
      }
    }
#pragma unroll
    for (int t = 0; t < 4; ++t) {
#pragma unroll
      for (int c = 0; c < 2; ++c) {
        int col = cbase + 16 * c + lm;
        float bc = c ? bcol1 : bcol0;
#pragma unroll
        for (int g = 0; g < 4; ++g) {
          int row = r0 + 16 * t + lq * 4 + g;
          if (row < N) {
            float v = acc[t][c][g] + bc;
            hout[(size_t)row * F + col] = v;
            if (c) { bsum1 += v; bsq1 += v * v; }
            else   { bsum0 += v; bsq0 += v * v; }
          }
        }
      }
    }
  }
  atomicAdd(csum + cbase + lm, bsum0);
  atomicAdd(csumsq + cbase + lm, bsq0);
  atomicAdd(csum + cbase + 16 + lm, bsum1);
  atomicAdd(csumsq + cbase + 16 + lm, bsq1);
}

// -------- BN finalize --------
__global__ void k_bnstats(const float* __restrict__ sum, const float* __restrict__ sumsq,
                          const float* __restrict__ g, const float* __restrict__ be,
                          float* __restrict__ scale, float* __restrict__ shift, float invN) {
  int c = threadIdx.x;
  float mu = sum[c] * invN;
  float var = fmaxf(sumsq[c] * invN - mu * mu, 0.0f);
  float sc = g[c] * rsqrtf(var + 1e-5f);
  scale[c] = sc;
  shift[c] = be[c] - mu * sc;
}

// -------- BN apply + ReLU: fp32 h -> bf16 dst --------
__global__ __launch_bounds__(256) void k_bnrelu(const float* __restrict__ h,
                                                unsigned short* __restrict__ dst,
                                                const float* __restrict__ scale,
                                                const float* __restrict__ shift, int n4) {
  int i = blockIdx.x * 256 + threadIdx.x;
  if (i >= n4) return;
  float4 v = ((const float4*)h)[i];
  int g = i & 31;
  float4 sc = ((const float4*)scale)[g];
  float4 sh = ((const float4*)shift)[g];
  ushort4 o = make_ushort4(f2bf(fmaxf(fmaf(v.x, sc.x, sh.x), 0.f)),
                           f2bf(fmaxf(fmaf(v.y, sc.y, sh.y), 0.f)),
                           f2bf(fmaxf(fmaf(v.z, sc.z, sh.z), 0.f)),
                           f2bf(fmaxf(fmaf(v.w, sc.w, sh.w), 0.f)));
  ((ushort4*)dst)[i] = o;
}

// -------- final linear 128 -> 2 (bf16 input) --------
__global__ __launch_bounds__(256) void k_out(const unsigned short* __restrict__ h,
                                             const float* __restrict__ Wout,
                                             const float* __restrict__ bout,
                                             float* __restrict__ out, int N) {
  __shared__ float W0[F], W1[F];
  if (threadIdx.x < F) {
    W0[threadIdx.x] = Wout[threadIdx.x * 2];
    W1[threadIdx.x] = Wout[threadIdx.x * 2 + 1];
  }
  __syncthreads();
  int r = blockIdx.x * 256 + threadIdx.x;
  if (r >= N) return;
  float a0 = bout[0];
  float a1 = bout[1];
  const uint4* hr = (const uint4*)(h + (size_t)r * F);
#pragma unroll 4
  for (int q = 0; q < 16; ++q) {
    uint4 u = hr[q];
    float v[8] = {bf_lo(u.x), bf_hi(u.x), bf_lo(u.y), bf_hi(u.y),
                  bf_lo(u.z), bf_hi(u.z), bf_lo(u.w), bf_hi(u.w)};
#pragma unroll
    for (int j = 0; j < 8; ++j) {
      a0 += v[j] * W0[8 * q + j];
      a1 += v[j] * W1[8 * q + j];
    }
  }
  out[2 * r] = a0;
  out[2 * r + 1] = a1;
}

extern "C" void kernel_launch(void* const* d_in, const int* in_sizes, int n_in,
                              void* d_out, int out_size, void* d_ws, size_t ws_size,
                              hipStream_t stream) {
  const float* x   = (const float*)d_in[0];
  const int*   eix = (const int*)d_in[1];
  const float* Wl0 = (const float*)d_in[2];
  const float* Wr0 = (const float*)d_in[3];
  const float* b0  = (const float*)d_in[4];
  const float* g0  = (const float*)d_in[5];
  const float* be0 = (const float*)d_in[6];
  const float* Wl1 = (const float*)d_in[7];
  const float* Wr1 = (const float*)d_in[8];
  const float* b1  = (const float*)d_in[9];
  const float* g1  = (const float*)d_in[10];
  const float* be1 = (const float*)d_in[11];
  const float* Wo  = (const float*)d_in[12];
  const float* bo  = (const float*)d_in[13];

  int N = in_sizes[0] / F;     // 50000
  int E = in_sizes[1] / 2;     // 600000
  const int* src  = eix;
  const int* dstv = eix + E;

  int nRowBlocks = (N + 63) / 64;         // 782
  size_t Npad = (size_t)nRowBlocks * 64;  // 50048

  // ws layout: aggb bf16[Npad*F] | xb bf16[Npad*F] | WcatT0 | WcatT1 | stats(768 f32) | h f32[N*F]
  unsigned short* aggb   = (unsigned short*)d_ws;
  unsigned short* xb     = aggb + Npad * F;
  unsigned short* WcatT0 = xb + Npad * F;
  unsigned short* WcatT1 = WcatT0 + 256 * F;
  float* stats = (float*)(WcatT1 + 256 * F);   // sum0, sq0, sum1, sq1 (128 each)
  float* scale = stats + 512;
  float* shift = scale + F;
  float* h     = shift + F;                    // N*F fp32
  // aliases:
  int* A    = (int*)d_out;       // N ints; dead before k_out writes d_out
  int* temp = (int*)h;           // src copy; h dead until gemm0
  int* adj  = (int*)d_in[1];     // overwrites src half; src preserved in temp

  hipMemsetAsync(A, 0, (size_t)N * sizeof(int), stream);
  hipMemsetAsync(stats, 0, 768 * sizeof(float), stream);
  hipMemcpyAsync(temp, src, (size_t)E * sizeof(int), hipMemcpyDeviceToDevice, stream);

  // ---- CSR build (shared by both layers) ----
  k_count<<<(E + 255) / 256, 256, 0, stream>>>(dstv, A, E);
  k_scan<<<1, 1024, 0, stream>>>(A, N);
  k_fill<<<(E + 255) / 256, 256, 0, stream>>>(temp, dstv, A, adj, E);

  // ---- weight prep + x conversion ----
  k_prepw<<<128, 256, 0, stream>>>(Wl0, Wr0, WcatT0);
  k_prepw<<<128, 256, 0, stream>>>(Wl1, Wr1, WcatT1);
  int n4 = N * F / 4;
  k_cvt<<<(n4 + 255) / 256, 256, 0, stream>>>(x, xb, n4);

  // ---- layer 0 ----
  k_gather<<<(N + 3) / 4, 256, 0, stream>>>(xb, A, adj, aggb, N);
  k_gemm<<<nRowBlocks, 256, 0, stream>>>(aggb, xb, WcatT0, b0, h, stats, stats + 128, N, nRowBlocks);
  k_bnstats<<<1, 128, 0, stream>>>(stats, stats + 128, g0, be0, scale, shift, 1.0f / N);
  k_bnrelu<<<(n4 + 255) / 256, 256, 0, stream>>>(h, xb, scale, shift, n4);  // h0b -> xb

  // ---- layer 1 ----
  k_gather<<<(N + 3) / 4, 256, 0, stream>>>(xb, A, adj, aggb, N);
  k_gemm<<<nRowBlocks, 256, 0, stream>>>(aggb, xb, WcatT1, b1, h, stats + 256, stats + 384, N, nRowBlocks);
  k_bnstats<<<1, 128, 0, stream>>>(stats + 256, stats + 384, g1, be1, scale, shift, 1.0f / N);
  k_bnrelu<<<(n4 + 255) / 256, 256, 0, stream>>>(h, aggb, scale, shift, n4); // h1b -> aggb

  // ---- output head ----
  k_out<<<(N + 255) / 256, 256, 0, stream>>>(aggb, Wo, bo, (float*)d_out, N);
}

// Round 6
// 426.164 us; speedup vs baseline: 1.9939x; 1.9939x over previous
//
#include <hip/hip_runtime.h>
#include <hip/hip_bf16.h>

#define F 128

typedef __attribute__((ext_vector_type(8))) short short8;    // 8 bf16 = 4 VGPRs
typedef __attribute__((ext_vector_type(4))) float floatx4;   // MFMA C/D

__device__ __forceinline__ float bf_lo(unsigned u) { return __uint_as_float(u << 16); }
__device__ __forceinline__ float bf_hi(unsigned u) { return __uint_as_float(u & 0xffff0000u); }

// fp32 -> bf16 bits, round-to-nearest-even
__device__ __forceinline__ unsigned short f2bf(float x) {
  unsigned u = __float_as_uint(x);
  u += 0x7fffu + ((u >> 16) & 1u);
  return (unsigned short)(u >> 16);
}

// -------- CSR build step 1: histogram of dst (12 atomics/addr avg — fine) --------
__global__ __launch_bounds__(256) void k_count(const int* __restrict__ dst,
                                               int* __restrict__ A, int E) {
  int e = blockIdx.x * 256 + threadIdx.x;
  if (e < E) atomicAdd(&A[dst[e]], 1);
}

// -------- CSR build step 2: in-place exclusive scan (single 1024-thread block) --------
__global__ __launch_bounds__(1024) void k_scan(int* __restrict__ A, int n) {
  __shared__ int wtot[16];
  int t = threadIdx.x, l = t & 63, w = t >> 6;
  int base = 0;
  for (int i0 = 0; i0 < n; i0 += 1024) {
    int i = i0 + t;
    int v = (i < n) ? A[i] : 0;
    int acc = v;
#pragma unroll
    for (int off = 1; off < 64; off <<= 1) {
      int u = __shfl_up(acc, off);
      if (l >= off) acc += u;
    }
    if (l == 63) wtot[w] = acc;
    __syncthreads();
    int woff = 0, total = 0;
#pragma unroll
    for (int ww = 0; ww < 16; ++ww) {
      total += wtot[ww];
      if (ww < w) woff += wtot[ww];
    }
    if (i < n) A[i] = base + woff + (acc - v);
    base += total;
    __syncthreads();
  }
}

// -------- CSR build step 3: fill adjacency; A becomes row-end (inclusive) --------
__global__ __launch_bounds__(256) void k_fill(const int* __restrict__ srcT,
                                              const int* __restrict__ dst,
                                              int* __restrict__ A, int* __restrict__ adj, int E) {
  int e = blockIdx.x * 256 + threadIdx.x;
  if (e >= E) return;
  int s = srcT[e], d = dst[e];
  int slot = atomicAdd(&A[d], 1);
  adj[slot] = s;
}

// -------- weight prep: WcatT[n][k] bf16, k in [0,256) = [Wl ; Wr] --------
__global__ __launch_bounds__(256) void k_prepw(const float* __restrict__ Wl,
                                               const float* __restrict__ Wr,
                                               unsigned short* __restrict__ WcatT) {
  int i = blockIdx.x * 256 + threadIdx.x;
  if (i >= 256 * F) return;
  int k = i >> 7, n = i & (F - 1);
  float v = (k < F) ? Wl[k * F + n] : Wr[(k - F) * F + n];
  WcatT[(size_t)n * 256 + k] = f2bf(v);
}

// -------- fp32 -> bf16 convert (x -> xb) --------
__global__ __launch_bounds__(256) void k_cvt(const float* __restrict__ x,
                                             unsigned short* __restrict__ xb, int n4) {
  int i = blockIdx.x * 256 + threadIdx.x;
  if (i >= n4) return;
  float4 v = ((const float4*)x)[i];
  ushort4 o = make_ushort4(f2bf(v.x), f2bf(v.y), f2bf(v.z), f2bf(v.w));
  ((ushort4*)xb)[i] = o;
}

// -------- mean aggregation by gather: one wave per dst row; bf16 in/out --------
__global__ __launch_bounds__(256) void k_gather(const unsigned short* __restrict__ xin,
                                                const int* __restrict__ A,
                                                const int* __restrict__ adj,
                                                unsigned short* __restrict__ aggb, int N) {
  int d = blockIdx.x * 4 + (threadIdx.x >> 6);
  if (d >= N) return;
  int l = threadIdx.x & 63;
  int e0 = (d == 0) ? 0 : A[d - 1];
  int e1 = A[d];
  int deg = e1 - e0;
  float2 acc = make_float2(0.f, 0.f);
  int ids = (e0 + l < e1) ? adj[e0 + l] : 0;
  int m = min(deg, 64);
  for (int j = 0; j < m; ++j) {
    int s = __shfl(ids, j);
    unsigned u = ((const unsigned*)xin)[(size_t)s * 64 + l];
    acc.x += bf_lo(u);
    acc.y += bf_hi(u);
  }
  for (int e = e0 + 64; e < e1; ++e) {
    int s = adj[e];
    unsigned u = ((const unsigned*)xin)[(size_t)s * 64 + l];
    acc.x += bf_lo(u);
    acc.y += bf_hi(u);
  }
  float inv = 1.0f / fmaxf((float)deg, 1.0f);
  unsigned out = (unsigned)f2bf(acc.x * inv) | ((unsigned)f2bf(acc.y * inv) << 16);
  ((unsigned*)aggb)[(size_t)d * 64 + l] = out;
}

// -------- MFMA gemm: h[N][128] = [aggb | xb] @ Wcat + bias; BN partials to pbuf --------
// 4 waves/block; wave w owns cols [32w, 32w+32). B fragments in registers.
// BN stats: NO ATOMICS. R3/R4/R5 were all bound by the same-address atomicAdd
// chain on csum/csumsq (~200 cyc per same-address L2 RMW; dur == 0.343 µs/block
// across rounds regardless of per-block work). Per-block partials are stored to
// pbuf[block][256] after an in-wave shfl_xor reduction; k_bnstats reduces pbuf.
__global__ __launch_bounds__(256, 2) void k_gemm(
    const unsigned short* __restrict__ aggb, const unsigned short* __restrict__ xb,
    const unsigned short* __restrict__ WcatT, const float* __restrict__ bias,
    float* __restrict__ hout, float* __restrict__ pbuf,
    int N, int nRowBlocks) {
  const int w = threadIdx.x >> 6;
  const int l = threadIdx.x & 63;
  const int lm = l & 15;   // tile row (A) / tile col (B, C/D)
  const int lq = l >> 4;   // quad
  const int cbase = 32 * w;

  // B fragments: [ctile][kstep]; lane holds B[k = 32s + 8*lq + j][n = cbase + 16c + lm]
  short8 bfrag[2][8];
#pragma unroll
  for (int c = 0; c < 2; ++c) {
    int col = cbase + 16 * c + lm;
    const unsigned short* wp = WcatT + (size_t)col * 256 + lq * 8;
#pragma unroll
    for (int s = 0; s < 8; ++s) bfrag[c][s] = *(const short8*)(wp + 32 * s);
  }
  float bcol0 = bias[cbase + lm];
  float bcol1 = bias[cbase + 16 + lm];
  float bsum0 = 0.f, bsum1 = 0.f, bsq0 = 0.f, bsq1 = 0.f;

  for (int rb = blockIdx.x; rb < nRowBlocks; rb += gridDim.x) {
    int r0 = rb * 64;
    floatx4 acc[4][2] = {};
#pragma unroll
    for (int t = 0; t < 4; ++t) {
      int r = r0 + 16 * t + lm;  // pad rows exist; stores/stats guarded
      const unsigned short* arow = aggb + (size_t)r * F + lq * 8;
      const unsigned short* xrow = xb + (size_t)r * F + lq * 8;
      short8 af[8];
#pragma unroll
      for (int s = 0; s < 4; ++s) {
        af[s] = *(const short8*)(arow + 32 * s);
        af[s + 4] = *(const short8*)(xrow + 32 * s);
      }
#pragma unroll
      for (int s = 0; s < 8; ++s) {
        acc[t][0] = __builtin_amdgcn_mfma_f32_16x16x32_bf16(af[s], bfrag[0][s], acc[t][0], 0, 0, 0);
        acc[t][1] = __builtin_amdgcn_mfma_f32_16x16x32_bf16(af[s], bfrag[1][s], acc[t][1], 0, 0, 0);
      }
    }
#pragma unroll
    for (int t = 0; t < 4; ++t) {
#pragma unroll
      for (int c = 0; c < 2; ++c) {
        int col = cbase + 16 * c + lm;
        float bc = c ? bcol1 : bcol0;
#pragma unroll
        for (int g = 0; g < 4; ++g) {
          int row = r0 + 16 * t + lq * 4 + g;
          if (row < N) {
            float v = acc[t][c][g] + bc;
            hout[(size_t)row * F + col] = v;
            if (c) { bsum1 += v; bsq1 += v * v; }
            else   { bsum0 += v; bsq0 += v * v; }
          }
        }
      }
    }
  }
  // in-wave reduce across the 4 lanes (lq = 0..3) sharing each column
  bsum0 += __shfl_xor(bsum0, 16); bsum0 += __shfl_xor(bsum0, 32);
  bsq0  += __shfl_xor(bsq0, 16);  bsq0  += __shfl_xor(bsq0, 32);
  bsum1 += __shfl_xor(bsum1, 16); bsum1 += __shfl_xor(bsum1, 32);
  bsq1  += __shfl_xor(bsq1, 16);  bsq1  += __shfl_xor(bsq1, 32);
  if (lq == 0) {
    float* pb = pbuf + (size_t)blockIdx.x * 256;
    pb[cbase + lm]            = bsum0;
    pb[128 + cbase + lm]      = bsq0;
    pb[cbase + 16 + lm]       = bsum1;
    pb[128 + cbase + 16 + lm] = bsq1;
  }
}

// -------- BN finalize: reduce per-block partials, compute scale/shift --------
__global__ __launch_bounds__(1024) void k_bnstats(const float* __restrict__ pbuf,
                                                  const float* __restrict__ g,
                                                  const float* __restrict__ be,
                                                  float* __restrict__ scale,
                                                  float* __restrict__ shift,
                                                  float invN, int nb) {
  __shared__ float sS[1024], sQ[1024];
  int t = threadIdx.x, c = t & 127, sub = t >> 7;
  float s = 0.f, q = 0.f;
  for (int b = sub; b < nb; b += 8) {
    s += pbuf[(size_t)b * 256 + c];
    q += pbuf[(size_t)b * 256 + 128 + c];
  }
  sS[t] = s; sQ[t] = q;
  __syncthreads();
#pragma unroll
  for (int st = 4; st >= 1; st >>= 1) {
    if (sub < st) { sS[t] += sS[t + st * 128]; sQ[t] += sQ[t + st * 128]; }
    __syncthreads();
  }
  if (t < 128) {
    float mu = sS[t] * invN;
    float var = fmaxf(sQ[t] * invN - mu * mu, 0.0f);
    float sc = g[t] * rsqrtf(var + 1e-5f);
    scale[t] = sc;
    shift[t] = be[t] - mu * sc;
  }
}

// -------- BN apply + ReLU: fp32 h -> bf16 dst --------
__global__ __launch_bounds__(256) void k_bnrelu(const float* __restrict__ h,
                                                unsigned short* __restrict__ dst,
                                                const float* __restrict__ scale,
                                                const float* __restrict__ shift, int n4) {
  int i = blockIdx.x * 256 + threadIdx.x;
  if (i >= n4) return;
  float4 v = ((const float4*)h)[i];
  int g = i & 31;
  float4 sc = ((const float4*)scale)[g];
  float4 sh = ((const float4*)shift)[g];
  ushort4 o = make_ushort4(f2bf(fmaxf(fmaf(v.x, sc.x, sh.x), 0.f)),
                           f2bf(fmaxf(fmaf(v.y, sc.y, sh.y), 0.f)),
                           f2bf(fmaxf(fmaf(v.z, sc.z, sh.z), 0.f)),
                           f2bf(fmaxf(fmaf(v.w, sc.w, sh.w), 0.f)));
  ((ushort4*)dst)[i] = o;
}

// -------- final linear 128 -> 2 (bf16 input) --------
__global__ __launch_bounds__(256) void k_out(const unsigned short* __restrict__ h,
                                             const float* __restrict__ Wout,
                                             const float* __restrict__ bout,
                                             float* __restrict__ out, int N) {
  __shared__ float W0[F], W1[F];
  if (threadIdx.x < F) {
    W0[threadIdx.x] = Wout[threadIdx.x * 2];
    W1[threadIdx.x] = Wout[threadIdx.x * 2 + 1];
  }
  __syncthreads();
  int r = blockIdx.x * 256 + threadIdx.x;
  if (r >= N) return;
  float a0 = bout[0];
  float a1 = bout[1];
  const uint4* hr = (const uint4*)(h + (size_t)r * F);
#pragma unroll 4
  for (int q = 0; q < 16; ++q) {
    uint4 u = hr[q];
    float v[8] = {bf_lo(u.x), bf_hi(u.x), bf_lo(u.y), bf_hi(u.y),
                  bf_lo(u.z), bf_hi(u.z), bf_lo(u.w), bf_hi(u.w)};
#pragma unroll
    for (int j = 0; j < 8; ++j) {
      a0 += v[j] * W0[8 * q + j];
      a1 += v[j] * W1[8 * q + j];
    }
  }
  out[2 * r] = a0;
  out[2 * r + 1] = a1;
}

extern "C" void kernel_launch(void* const* d_in, const int* in_sizes, int n_in,
                              void* d_out, int out_size, void* d_ws, size_t ws_size,
                              hipStream_t stream) {
  const float* x   = (const float*)d_in[0];
  const int*   eix = (const int*)d_in[1];
  const float* Wl0 = (const float*)d_in[2];
  const float* Wr0 = (const float*)d_in[3];
  const float* b0  = (const float*)d_in[4];
  const float* g0  = (const float*)d_in[5];
  const float* be0 = (const float*)d_in[6];
  const float* Wl1 = (const float*)d_in[7];
  const float* Wr1 = (const float*)d_in[8];
  const float* b1  = (const float*)d_in[9];
  const float* g1  = (const float*)d_in[10];
  const float* be1 = (const float*)d_in[11];
  const float* Wo  = (const float*)d_in[12];
  const float* bo  = (const float*)d_in[13];

  int N = in_sizes[0] / F;     // 50000
  int E = in_sizes[1] / 2;     // 600000
  const int* src  = eix;
  const int* dstv = eix + E;

  int nRowBlocks = (N + 63) / 64;         // 782
  size_t Npad = (size_t)nRowBlocks * 64;  // 50048

  // ws layout: aggb bf16[Npad*F] | xb bf16[Npad*F] | WcatT0 | WcatT1 | scale | shift | h f32[N*F]
  unsigned short* aggb   = (unsigned short*)d_ws;
  unsigned short* xb     = aggb + Npad * F;
  unsigned short* WcatT0 = xb + Npad * F;
  unsigned short* WcatT1 = WcatT0 + 256 * F;
  float* scale = (float*)(WcatT1 + 256 * F);
  float* shift = scale + F;
  float* h     = shift + F;                    // N*F fp32
  // aliases:
  int*   A    = (int*)d_out;        // N ints; dead before k_out writes d_out
  int*   temp = (int*)h;            // src copy; h dead until gemm0
  int*   adj  = (int*)d_in[1];      // overwrites src half; src preserved in temp
  float* pbuf = (float*)(eix + E);  // BN partials [nRowBlocks][256] over dead dst half (2.4 MB > 800 KB)

  hipMemsetAsync(A, 0, (size_t)N * sizeof(int), stream);
  hipMemcpyAsync(temp, src, (size_t)E * sizeof(int), hipMemcpyDeviceToDevice, stream);

  // ---- CSR build (shared by both layers; dstv dead afterwards -> pbuf) ----
  k_count<<<(E + 255) / 256, 256, 0, stream>>>(dstv, A, E);
  k_scan<<<1, 1024, 0, stream>>>(A, N);
  k_fill<<<(E + 255) / 256, 256, 0, stream>>>(temp, dstv, A, adj, E);

  // ---- weight prep + x conversion ----
  k_prepw<<<128, 256, 0, stream>>>(Wl0, Wr0, WcatT0);
  k_prepw<<<128, 256, 0, stream>>>(Wl1, Wr1, WcatT1);
  int n4 = N * F / 4;
  k_cvt<<<(n4 + 255) / 256, 256, 0, stream>>>(x, xb, n4);

  // ---- layer 0 ----
  k_gather<<<(N + 3) / 4, 256, 0, stream>>>(xb, A, adj, aggb, N);
  k_gemm<<<nRowBlocks, 256, 0, stream>>>(aggb, xb, WcatT0, b0, h, pbuf, N, nRowBlocks);
  k_bnstats<<<1, 1024, 0, stream>>>(pbuf, g0, be0, scale, shift, 1.0f / N, nRowBlocks);
  k_bnrelu<<<(n4 + 255) / 256, 256, 0, stream>>>(h, xb, scale, shift, n4);  // h0b -> xb

  // ---- layer 1 ----
  k_gather<<<(N + 3) / 4, 256, 0, stream>>>(xb, A, adj, aggb, N);
  k_gemm<<<nRowBlocks, 256, 0, stream>>>(aggb, xb, WcatT1, b1, h, pbuf, N, nRowBlocks);
  k_bnstats<<<1, 1024, 0, stream>>>(pbuf, g1, be1, scale, shift, 1.0f / N, nRowBlocks);
  k_bnrelu<<<(n4 + 255) / 256, 256, 0, stream>>>(h, aggb, scale, shift, n4); // h1b -> aggb

  // ---- output head ----
  k_out<<<(N + 255) / 256, 256, 0, stream>>>(aggb, Wo, bo, (float*)d_out, N);
}

// Round 7
// 388.962 us; speedup vs baseline: 2.1846x; 1.0956x over previous
//
#include <hip/hip_runtime.h>
#include <hip/hip_bf16.h>

#define F 128

typedef __attribute__((ext_vector_type(8))) short short8;    // 8 bf16 = 4 VGPRs
typedef __attribute__((ext_vector_type(4))) float floatx4;   // MFMA C/D

__device__ __forceinline__ float bf_lo(unsigned u) { return __uint_as_float(u << 16); }
__device__ __forceinline__ float bf_hi(unsigned u) { return __uint_as_float(u & 0xffff0000u); }

// fp32 -> bf16 bits, round-to-nearest-even
__device__ __forceinline__ unsigned short f2bf(float x) {
  unsigned u = __float_as_uint(x);
  u += 0x7fffu + ((u >> 16) & 1u);
  return (unsigned short)(u >> 16);
}

// -------- CSR build step 1: histogram of dst (~12 atomics/addr avg — fine) --------
__global__ __launch_bounds__(256) void k_count(const int* __restrict__ dst,
                                               int* __restrict__ A, int E) {
  int e = blockIdx.x * 256 + threadIdx.x;
  if (e < E) atomicAdd(&A[dst[e]], 1);
}

// -------- scan phase A: per-block exclusive scan + block totals --------
// (R6's single-block scan was 46 us of serial latency — top dispatch)
__global__ __launch_bounds__(1024) void k_scanA(int* __restrict__ A,
                                                int* __restrict__ bsum, int n) {
  __shared__ int wtot[16];
  int t = threadIdx.x, l = t & 63, w = t >> 6;
  int i = blockIdx.x * 1024 + t;
  int v = (i < n) ? A[i] : 0;
  int acc = v;
#pragma unroll
  for (int off = 1; off < 64; off <<= 1) {
    int u = __shfl_up(acc, off);
    if (l >= off) acc += u;
  }
  if (l == 63) wtot[w] = acc;
  __syncthreads();
  int woff = 0, total = 0;
#pragma unroll
  for (int ww = 0; ww < 16; ++ww) {
    total += wtot[ww];
    if (ww < w) woff += wtot[ww];
  }
  if (i < n) A[i] = woff + (acc - v);  // block-local exclusive
  if (t == 0) bsum[blockIdx.x] = total;
}

// -------- scan phase B: one wave scans the <=64 block totals (exclusive) --------
__global__ void k_scanB(int* __restrict__ bsum, int nb) {
  int t = threadIdx.x;  // 64 threads
  int v = (t < nb) ? bsum[t] : 0;
  int acc = v;
#pragma unroll
  for (int off = 1; off < 64; off <<= 1) {
    int u = __shfl_up(acc, off);
    if (t >= off) acc += u;
  }
  if (t < nb) bsum[t] = acc - v;
}

// -------- scan phase C: add block bases --------
__global__ __launch_bounds__(1024) void k_scanC(int* __restrict__ A,
                                                const int* __restrict__ bsum, int n) {
  int i = blockIdx.x * 1024 + threadIdx.x;
  if (i < n) A[i] += bsum[blockIdx.x];
}

// -------- CSR build step 3: fill adjacency; A becomes row-end (inclusive) --------
__global__ __launch_bounds__(256) void k_fill(const int* __restrict__ srcT,
                                              const int* __restrict__ dst,
                                              int* __restrict__ A, int* __restrict__ adj, int E) {
  int e = blockIdx.x * 256 + threadIdx.x;
  if (e >= E) return;
  int s = srcT[e], d = dst[e];
  int slot = atomicAdd(&A[d], 1);
  adj[slot] = s;
}

// -------- weight prep (both layers): WcatT[n][k] bf16, k in [0,256) = [Wl ; Wr] --------
__global__ __launch_bounds__(256) void k_prepw(const float* __restrict__ Wl0,
                                               const float* __restrict__ Wr0,
                                               const float* __restrict__ Wl1,
                                               const float* __restrict__ Wr1,
                                               unsigned short* __restrict__ WcatT0,
                                               unsigned short* __restrict__ WcatT1) {
  int i = blockIdx.x * 256 + threadIdx.x;
  int layer = i >= 256 * F;
  int j = i & (256 * F - 1);
  int k = j >> 7, n = j & (F - 1);
  const float* Wl = layer ? Wl1 : Wl0;
  const float* Wr = layer ? Wr1 : Wr0;
  unsigned short* WcatT = layer ? WcatT1 : WcatT0;
  float v = (k < F) ? Wl[k * F + n] : Wr[(k - F) * F + n];
  WcatT[(size_t)n * 256 + k] = f2bf(v);
}

// -------- fp32 -> bf16 convert (x -> xb) --------
__global__ __launch_bounds__(256) void k_cvt(const float* __restrict__ x,
                                             unsigned short* __restrict__ xb, int n4) {
  int i = blockIdx.x * 256 + threadIdx.x;
  if (i >= n4) return;
  float4 v = ((const float4*)x)[i];
  ushort4 o = make_ushort4(f2bf(v.x), f2bf(v.y), f2bf(v.z), f2bf(v.w));
  ((ushort4*)xb)[i] = o;
}

// -------- mean aggregation by gather: one wave per dst row; bf16 in/out --------
__global__ __launch_bounds__(256) void k_gather(const unsigned short* __restrict__ xin,
                                                const int* __restrict__ A,
                                                const int* __restrict__ adj,
                                                unsigned short* __restrict__ aggb, int N) {
  int d = blockIdx.x * 4 + (threadIdx.x >> 6);
  if (d >= N) return;
  int l = threadIdx.x & 63;
  int e0 = (d == 0) ? 0 : A[d - 1];
  int e1 = A[d];
  int deg = e1 - e0;
  float2 acc = make_float2(0.f, 0.f);
  int ids = (e0 + l < e1) ? adj[e0 + l] : 0;
  int m = min(deg, 64);
  for (int j = 0; j < m; ++j) {
    int s = __shfl(ids, j);
    unsigned u = ((const unsigned*)xin)[(size_t)s * 64 + l];
    acc.x += bf_lo(u);
    acc.y += bf_hi(u);
  }
  for (int e = e0 + 64; e < e1; ++e) {
    int s = adj[e];
    unsigned u = ((const unsigned*)xin)[(size_t)s * 64 + l];
    acc.x += bf_lo(u);
    acc.y += bf_hi(u);
  }
  float inv = 1.0f / fmaxf((float)deg, 1.0f);
  unsigned out = (unsigned)f2bf(acc.x * inv) | ((unsigned)f2bf(acc.y * inv) << 16);
  ((unsigned*)aggb)[(size_t)d * 64 + l] = out;
}

// -------- MFMA gemm: hb[N][128] = bf16([aggb | xb] @ Wcat + bias); BN partials to pbuf --------
// 4 waves/block; wave w owns cols [32w, 32w+32). B fragments in registers.
// NO same-address atomics anywhere (R3-R5 were bound by the csum atomic chain:
// 0.343 us/block constant). Partials: shfl_xor reduce -> pbuf[block][256] -> k_bnstats.
__global__ __launch_bounds__(256, 2) void k_gemm(
    const unsigned short* __restrict__ aggb, const unsigned short* __restrict__ xb,
    const unsigned short* __restrict__ WcatT, const float* __restrict__ bias,
    unsigned short* __restrict__ hb, float* __restrict__ pbuf, int N) {
  const int w = threadIdx.x >> 6;
  const int l = threadIdx.x & 63;
  const int lm = l & 15;   // tile row (A) / tile col (B, C/D)
  const int lq = l >> 4;   // quad
  const int cbase = 32 * w;

  // B fragments: [ctile][kstep]; lane holds B[k = 32s + 8*lq + j][n = cbase + 16c + lm]
  short8 bfrag[2][8];
#pragma unroll
  for (int c = 0; c < 2; ++c) {
    int col = cbase + 16 * c + lm;
    const unsigned short* wp = WcatT + (size_t)col * 256 + lq * 8;
#pragma unroll
    for (int s = 0; s < 8; ++s) bfrag[c][s] = *(const short8*)(wp + 32 * s);
  }
  float bcol0 = bias[cbase + lm];
  float bcol1 = bias[cbase + 16 + lm];
  float bsum0 = 0.f, bsum1 = 0.f, bsq0 = 0.f, bsq1 = 0.f;

  int r0 = blockIdx.x * 64;  // grid == nRowBlocks
  floatx4 acc[4][2] = {};
#pragma unroll
  for (int t = 0; t < 4; ++t) {
    int r = r0 + 16 * t + lm;  // pad rows exist (0xAA = tiny bf16); stores/stats guarded
    const unsigned short* arow = aggb + (size_t)r * F + lq * 8;
    const unsigned short* xrow = xb + (size_t)r * F + lq * 8;
    short8 af[8];
#pragma unroll
    for (int s = 0; s < 4; ++s) {
      af[s] = *(const short8*)(arow + 32 * s);
      af[s + 4] = *(const short8*)(xrow + 32 * s);
    }
#pragma unroll
    for (int s = 0; s < 8; ++s) {
      acc[t][0] = __builtin_amdgcn_mfma_f32_16x16x32_bf16(af[s], bfrag[0][s], acc[t][0], 0, 0, 0);
      acc[t][1] = __builtin_amdgcn_mfma_f32_16x16x32_bf16(af[s], bfrag[1][s], acc[t][1], 0, 0, 0);
    }
  }
#pragma unroll
  for (int t = 0; t < 4; ++t) {
#pragma unroll
    for (int c = 0; c < 2; ++c) {
      int col = cbase + 16 * c + lm;
      float bc = c ? bcol1 : bcol0;
#pragma unroll
      for (int g = 0; g < 4; ++g) {
        int row = r0 + 16 * t + lq * 4 + g;
        if (row < N) {
          float v = acc[t][c][g] + bc;
          hb[(size_t)row * F + col] = f2bf(v);  // stats from fp32 v, storage bf16
          if (c) { bsum1 += v; bsq1 += v * v; }
          else   { bsum0 += v; bsq0 += v * v; }
        }
      }
    }
  }
  // reduce across the 4 lane-quads sharing each column, then one store per column
  bsum0 += __shfl_xor(bsum0, 16); bsum0 += __shfl_xor(bsum0, 32);
  bsq0  += __shfl_xor(bsq0, 16);  bsq0  += __shfl_xor(bsq0, 32);
  bsum1 += __shfl_xor(bsum1, 16); bsum1 += __shfl_xor(bsum1, 32);
  bsq1  += __shfl_xor(bsq1, 16);  bsq1  += __shfl_xor(bsq1, 32);
  if (lq == 0) {
    float* pb = pbuf + (size_t)blockIdx.x * 256;
    pb[cbase + lm]            = bsum0;
    pb[128 + cbase + lm]      = bsq0;
    pb[cbase + 16 + lm]       = bsum1;
    pb[128 + cbase + 16 + lm] = bsq1;
  }
}

// -------- BN finalize: reduce per-block partials, compute scale/shift --------
__global__ __launch_bounds__(1024) void k_bnstats(const float* __restrict__ pbuf,
                                                  const float* __restrict__ g,
                                                  const float* __restrict__ be,
                                                  float* __restrict__ scale,
                                                  float* __restrict__ shift,
                                                  float invN, int nb) {
  __shared__ float sS[1024], sQ[1024];
  int t = threadIdx.x, c = t & 127, sub = t >> 7;
  float s = 0.f, q = 0.f;
  for (int b = sub; b < nb; b += 8) {
    s += pbuf[(size_t)b * 256 + c];
    q += pbuf[(size_t)b * 256 + 128 + c];
  }
  sS[t] = s; sQ[t] = q;
  __syncthreads();
#pragma unroll
  for (int st = 4; st >= 1; st >>= 1) {
    if (sub < st) { sS[t] += sS[t + st * 128]; sQ[t] += sQ[t + st * 128]; }
    __syncthreads();
  }
  if (t < 128) {
    float mu = sS[t] * invN;
    float var = fmaxf(sQ[t] * invN - mu * mu, 0.0f);
    float sc = g[t] * rsqrtf(var + 1e-5f);
    scale[t] = sc;
    shift[t] = be[t] - mu * sc;
  }
}

// -------- BN apply + ReLU: bf16 h -> bf16 dst (8 elems/thread) --------
__global__ __launch_bounds__(256) void k_bnrelu(const unsigned short* __restrict__ h,
                                                unsigned short* __restrict__ dst,
                                                const float* __restrict__ scale,
                                                const float* __restrict__ shift, int n8) {
  int i = blockIdx.x * 256 + threadIdx.x;
  if (i >= n8) return;
  uint4 u = ((const uint4*)h)[i];
  int g = i & 15;  // 16 threads per 128-col row, 8 cols each
  float4 sc0 = ((const float4*)scale)[2 * g];
  float4 sc1 = ((const float4*)scale)[2 * g + 1];
  float4 sh0 = ((const float4*)shift)[2 * g];
  float4 sh1 = ((const float4*)shift)[2 * g + 1];
  unsigned o0 = (unsigned)f2bf(fmaxf(fmaf(bf_lo(u.x), sc0.x, sh0.x), 0.f)) |
                ((unsigned)f2bf(fmaxf(fmaf(bf_hi(u.x), sc0.y, sh0.y), 0.f)) << 16);
  unsigned o1 = (unsigned)f2bf(fmaxf(fmaf(bf_lo(u.y), sc0.z, sh0.z), 0.f)) |
                ((unsigned)f2bf(fmaxf(fmaf(bf_hi(u.y), sc0.w, sh0.w), 0.f)) << 16);
  unsigned o2 = (unsigned)f2bf(fmaxf(fmaf(bf_lo(u.z), sc1.x, sh1.x), 0.f)) |
                ((unsigned)f2bf(fmaxf(fmaf(bf_hi(u.z), sc1.y, sh1.y), 0.f)) << 16);
  unsigned o3 = (unsigned)f2bf(fmaxf(fmaf(bf_lo(u.w), sc1.z, sh1.z), 0.f)) |
                ((unsigned)f2bf(fmaxf(fmaf(bf_hi(u.w), sc1.w, sh1.w), 0.f)) << 16);
  ((uint4*)dst)[i] = make_uint4(o0, o1, o2, o3);
}

// -------- final linear 128 -> 2 (bf16 input) --------
__global__ __launch_bounds__(256) void k_out(const unsigned short* __restrict__ h,
                                             const float* __restrict__ Wout,
                                             const float* __restrict__ bout,
                                             float* __restrict__ out, int N) {
  __shared__ float W0[F], W1[F];
  if (threadIdx.x < F) {
    W0[threadIdx.x] = Wout[threadIdx.x * 2];
    W1[threadIdx.x] = Wout[threadIdx.x * 2 + 1];
  }
  __syncthreads();
  int r = blockIdx.x * 256 + threadIdx.x;
  if (r >= N) return;
  float a0 = bout[0];
  float a1 = bout[1];
  const uint4* hr = (const uint4*)(h + (size_t)r * F);
#pragma unroll 4
  for (int q = 0; q < 16; ++q) {
    uint4 u = hr[q];
    float v[8] = {bf_lo(u.x), bf_hi(u.x), bf_lo(u.y), bf_hi(u.y),
                  bf_lo(u.z), bf_hi(u.z), bf_lo(u.w), bf_hi(u.w)};
#pragma unroll
    for (int j = 0; j < 8; ++j) {
      a0 += v[j] * W0[8 * q + j];
      a1 += v[j] * W1[8 * q + j];
    }
  }
  out[2 * r] = a0;
  out[2 * r + 1] = a1;
}

extern "C" void kernel_launch(void* const* d_in, const int* in_sizes, int n_in,
                              void* d_out, int out_size, void* d_ws, size_t ws_size,
                              hipStream_t stream) {
  const float* x   = (const float*)d_in[0];
  const int*   eix = (const int*)d_in[1];
  const float* Wl0 = (const float*)d_in[2];
  const float* Wr0 = (const float*)d_in[3];
  const float* b0  = (const float*)d_in[4];
  const float* g0  = (const float*)d_in[5];
  const float* be0 = (const float*)d_in[6];
  const float* Wl1 = (const float*)d_in[7];
  const float* Wr1 = (const float*)d_in[8];
  const float* b1  = (const float*)d_in[9];
  const float* g1  = (const float*)d_in[10];
  const float* be1 = (const float*)d_in[11];
  const float* Wo  = (const float*)d_in[12];
  const float* bo  = (const float*)d_in[13];

  int N = in_sizes[0] / F;     // 50000
  int E = in_sizes[1] / 2;     // 600000
  const int* src  = eix;
  const int* dstv = eix + E;

  int nRowBlocks = (N + 63) / 64;         // 782
  size_t Npad = (size_t)nRowBlocks * 64;  // 50048
  int nScanB = (N + 1023) / 1024;         // 49

  // ws layout (all scratch in ws; no input/output aliasing):
  // aggb | xb | hb (bf16, Npad*F each) | WcatT0 | WcatT1 | scale | shift | A | bsum | adj | pbuf
  unsigned short* aggb   = (unsigned short*)d_ws;
  unsigned short* xb     = aggb + Npad * F;
  unsigned short* hb     = xb + Npad * F;
  unsigned short* WcatT0 = hb + Npad * F;
  unsigned short* WcatT1 = WcatT0 + 256 * F;
  float* scale = (float*)(WcatT1 + 256 * F);
  float* shift = scale + F;
  int*   A     = (int*)(shift + F);
  int*   bsum  = A + N;
  int*   adj   = bsum + 64;
  float* pbuf  = (float*)(adj + E);   // [nRowBlocks][256]  (~41.9 MB total, ws >= 51.4 MB proven)

  hipMemsetAsync(A, 0, (size_t)N * sizeof(int), stream);

  // ---- CSR build (shared by both layers) ----
  k_count<<<(E + 255) / 256, 256, 0, stream>>>(dstv, A, E);
  k_scanA<<<nScanB, 1024, 0, stream>>>(A, bsum, N);
  k_scanB<<<1, 64, 0, stream>>>(bsum, nScanB);
  k_scanC<<<nScanB, 1024, 0, stream>>>(A, bsum, N);
  k_fill<<<(E + 255) / 256, 256, 0, stream>>>(src, dstv, A, adj, E);

  // ---- weight prep (both layers) + x conversion ----
  k_prepw<<<256, 256, 0, stream>>>(Wl0, Wr0, Wl1, Wr1, WcatT0, WcatT1);
  int n4 = N * F / 4, n8 = N * F / 8;
  k_cvt<<<(n4 + 255) / 256, 256, 0, stream>>>(x, xb, n4);

  // ---- layer 0 ----
  k_gather<<<(N + 3) / 4, 256, 0, stream>>>(xb, A, adj, aggb, N);
  k_gemm<<<nRowBlocks, 256, 0, stream>>>(aggb, xb, WcatT0, b0, hb, pbuf, N);
  k_bnstats<<<1, 1024, 0, stream>>>(pbuf, g0, be0, scale, shift, 1.0f / N, nRowBlocks);
  k_bnrelu<<<(n8 + 255) / 256, 256, 0, stream>>>(hb, xb, scale, shift, n8);  // -> xb

  // ---- layer 1 ----
  k_gather<<<(N + 3) / 4, 256, 0, stream>>>(xb, A, adj, aggb, N);
  k_gemm<<<nRowBlocks, 256, 0, stream>>>(aggb, xb, WcatT1, b1, hb, pbuf, N);
  k_bnstats<<<1, 1024, 0, stream>>>(pbuf, g1, be1, scale, shift, 1.0f / N, nRowBlocks);
  k_bnrelu<<<(n8 + 255) / 256, 256, 0, stream>>>(hb, aggb, scale, shift, n8); // -> aggb

  // ---- output head ----
  k_out<<<(N + 255) / 256, 256, 0, stream>>>(aggb, Wo, bo, (float*)d_out, N);
}

// Round 9
// 343.212 us; speedup vs baseline: 2.4758x; 1.1333x over previous
//
#include <hip/hip_runtime.h>
#include <hip/hip_bf16.h>

#define F 128

typedef __attribute__((ext_vector_type(8))) short short8;    // 8 bf16 = 4 VGPRs
typedef __attribute__((ext_vector_type(4))) float floatx4;   // MFMA C/D

__device__ __forceinline__ float bf_lo(unsigned u) { return __uint_as_float(u << 16); }
__device__ __forceinline__ float bf_hi(unsigned u) { return __uint_as_float(u & 0xffff0000u); }

// fp32 -> bf16 bits, round-to-nearest-even
__device__ __forceinline__ unsigned short f2bf(float x) {
  unsigned u = __float_as_uint(x);
  u += 0x7fffu + ((u >> 16) & 1u);
  return (unsigned short)(u >> 16);
}
__device__ __forceinline__ unsigned pack2(float a, float b) {
  return (unsigned)f2bf(a) | ((unsigned)f2bf(b) << 16);
}

// -------- CSR build step 1: histogram of dst (~12 atomics/addr avg — fine) --------
__global__ __launch_bounds__(256) void k_count(const int* __restrict__ dst,
                                               int* __restrict__ A, int E) {
  int e = blockIdx.x * 256 + threadIdx.x;
  if (e < E) atomicAdd(&A[dst[e]], 1);
}

// -------- scan phase A: per-block exclusive scan + block totals --------
__global__ __launch_bounds__(1024) void k_scanA(int* __restrict__ A,
                                                int* __restrict__ bsum, int n) {
  __shared__ int wtot[16];
  int t = threadIdx.x, l = t & 63, w = t >> 6;
  int i = blockIdx.x * 1024 + t;
  int v = (i < n) ? A[i] : 0;
  int acc = v;
#pragma unroll
  for (int off = 1; off < 64; off <<= 1) {
    int u = __shfl_up(acc, off);
    if (l >= off) acc += u;
  }
  if (l == 63) wtot[w] = acc;
  __syncthreads();
  int woff = 0, total = 0;
#pragma unroll
  for (int ww = 0; ww < 16; ++ww) {
    total += wtot[ww];
    if (ww < w) woff += wtot[ww];
  }
  if (i < n) A[i] = woff + (acc - v);  // block-local exclusive
  if (t == 0) bsum[blockIdx.x] = total;
}

// -------- scan phase C: every block re-scans the <=64 totals in-wave, adds base --------
__global__ __launch_bounds__(1024) void k_scanC(int* __restrict__ A,
                                                const int* __restrict__ bsum, int n, int nb) {
  __shared__ int sbase;
  int t = threadIdx.x;
  if (t < 64) {
    int v = (t < nb) ? bsum[t] : 0;
    int acc = v;
#pragma unroll
    for (int off = 1; off < 64; off <<= 1) {
      int u = __shfl_up(acc, off);
      if (t >= off) acc += u;
    }
    int base = (blockIdx.x == 0) ? 0 : __shfl(acc, blockIdx.x - 1);
    if (t == 0) sbase = base;
  }
  __syncthreads();
  int i = blockIdx.x * 1024 + t;
  if (i < n) A[i] += sbase;
}

// -------- CSR build step 3: fill adjacency; A becomes row-end (inclusive) --------
__global__ __launch_bounds__(256) void k_fill(const int* __restrict__ srcT,
                                              const int* __restrict__ dst,
                                              int* __restrict__ A, int* __restrict__ adj, int E) {
  int e = blockIdx.x * 256 + threadIdx.x;
  if (e >= E) return;
  int s = srcT[e], d = dst[e];
  int slot = atomicAdd(&A[d], 1);
  adj[slot] = s;
}

// -------- merged prep: x->bf16 convert + both weight transposes --------
__global__ __launch_bounds__(256) void k_prep(const float* __restrict__ x,
                                              const float* __restrict__ Wl0,
                                              const float* __restrict__ Wr0,
                                              const float* __restrict__ Wl1,
                                              const float* __restrict__ Wr1,
                                              unsigned short* __restrict__ xb,
                                              unsigned short* __restrict__ WcatT0,
                                              unsigned short* __restrict__ WcatT1, int n4) {
  int i = blockIdx.x * 256 + threadIdx.x;
  if (i < n4) {
    float4 v = ((const float4*)x)[i];
    ((ushort4*)xb)[i] = make_ushort4(f2bf(v.x), f2bf(v.y), f2bf(v.z), f2bf(v.w));
  } else {
    int j = i - n4;
    if (j < 2 * 256 * F) {
      int layer = j >> 15;
      int jj = j & 32767;
      int k = jj >> 7, n = jj & (F - 1);
      const float* Wl = layer ? Wl1 : Wl0;
      const float* Wr = layer ? Wr1 : Wr0;
      unsigned short* WT = layer ? WcatT1 : WcatT0;
      float v = (k < F) ? Wl[k * F + n] : Wr[(k - F) * F + n];
      WT[(size_t)n * 256 + k] = f2bf(v);
    }
  }
}

// -------- mean aggregation v2: one wave per dst row, 4 neighbors/iter --------
// 16 lanes x uint4 (16 B) cover one 256-B row (row = 128 bf16 = 16 uint4s —
// R8 BUG: used stride 32 uint4s = row 2s, and wrote row 2d, corrupting xb).
__global__ __launch_bounds__(256) void k_gather(const unsigned short* __restrict__ xin,
                                                const int* __restrict__ A,
                                                const int* __restrict__ adj,
                                                unsigned short* __restrict__ aggb, int N) {
  int d = blockIdx.x * 4 + (threadIdx.x >> 6);
  if (d >= N) return;
  int l = threadIdx.x & 63;
  int grp = l >> 4, ln = l & 15;
  int e0 = (d == 0) ? 0 : A[d - 1];
  int e1 = A[d];
  int deg = e1 - e0;
  const uint4* xrows = (const uint4*)xin;
  float acc[8] = {0.f, 0.f, 0.f, 0.f, 0.f, 0.f, 0.f, 0.f};
  if (deg > 0) {
    int ids = adj[min(e0 + l, e1 - 1)];
    int m = min(deg, 64);
    for (int j0 = 0; j0 < m; j0 += 4) {
      int jj = j0 + grp;
      int s = __shfl(ids, jj);
      if (jj < m) {
        uint4 u = xrows[(size_t)s * 16 + ln];
        acc[0] += bf_lo(u.x); acc[1] += bf_hi(u.x);
        acc[2] += bf_lo(u.y); acc[3] += bf_hi(u.y);
        acc[4] += bf_lo(u.z); acc[5] += bf_hi(u.z);
        acc[6] += bf_lo(u.w); acc[7] += bf_hi(u.w);
      }
    }
    for (int e = e0 + 64 + grp; e < e1; e += 4) {  // rare: deg > 64
      int s = adj[e];
      uint4 u = xrows[(size_t)s * 16 + ln];
      acc[0] += bf_lo(u.x); acc[1] += bf_hi(u.x);
      acc[2] += bf_lo(u.y); acc[3] += bf_hi(u.y);
      acc[4] += bf_lo(u.z); acc[5] += bf_hi(u.z);
      acc[6] += bf_lo(u.w); acc[7] += bf_hi(u.w);
    }
  }
#pragma unroll
  for (int k2 = 0; k2 < 8; ++k2) {
    acc[k2] += __shfl_xor(acc[k2], 16);
    acc[k2] += __shfl_xor(acc[k2], 32);
  }
  if (grp == 0) {
    float inv = 1.0f / fmaxf((float)deg, 1.0f);
    uint4 o = make_uint4(pack2(acc[0] * inv, acc[1] * inv), pack2(acc[2] * inv, acc[3] * inv),
                         pack2(acc[4] * inv, acc[5] * inv), pack2(acc[6] * inv, acc[7] * inv));
    ((uint4*)aggb)[(size_t)d * 16 + ln] = o;
  }
}

// -------- MFMA gemm: hb[N][128] = bf16([aggb | xb] @ Wcat + bias); BN partials to pbuf --------
// 4 waves/block; wave w owns cols [32w, 32w+32). B fragments in registers.
// NO same-address atomics (R3-R5 were bound by the csum atomic chain).
__global__ __launch_bounds__(256, 2) void k_gemm(
    const unsigned short* __restrict__ aggb, const unsigned short* __restrict__ xb,
    const unsigned short* __restrict__ WcatT, const float* __restrict__ bias,
    unsigned short* __restrict__ hb, float* __restrict__ pbuf, int N) {
  const int w = threadIdx.x >> 6;
  const int l = threadIdx.x & 63;
  const int lm = l & 15;   // tile row (A) / tile col (B, C/D)
  const int lq = l >> 4;   // quad
  const int cbase = 32 * w;

  short8 bfrag[2][8];
#pragma unroll
  for (int c = 0; c < 2; ++c) {
    int col = cbase + 16 * c + lm;
    const unsigned short* wp = WcatT + (size_t)col * 256 + lq * 8;
#pragma unroll
    for (int s = 0; s < 8; ++s) bfrag[c][s] = *(const short8*)(wp + 32 * s);
  }
  float bcol0 = bias[cbase + lm];
  float bcol1 = bias[cbase + 16 + lm];
  float bsum0 = 0.f, bsum1 = 0.f, bsq0 = 0.f, bsq1 = 0.f;

  int r0 = blockIdx.x * 64;  // grid == nRowBlocks
  floatx4 acc[4][2] = {};
#pragma unroll
  for (int t = 0; t < 4; ++t) {
    int r = r0 + 16 * t + lm;  // pad rows exist (poison = tiny bf16); stores/stats guarded
    const unsigned short* arow = aggb + (size_t)r * F + lq * 8;
    const unsigned short* xrow = xb + (size_t)r * F + lq * 8;
    short8 af[8];
#pragma unroll
    for (int s = 0; s < 4; ++s) {
      af[s] = *(const short8*)(arow + 32 * s);
      af[s + 4] = *(const short8*)(xrow + 32 * s);
    }
#pragma unroll
    for (int s = 0; s < 8; ++s) {
      acc[t][0] = __builtin_amdgcn_mfma_f32_16x16x32_bf16(af[s], bfrag[0][s], acc[t][0], 0, 0, 0);
      acc[t][1] = __builtin_amdgcn_mfma_f32_16x16x32_bf16(af[s], bfrag[1][s], acc[t][1], 0, 0, 0);
    }
  }
#pragma unroll
  for (int t = 0; t < 4; ++t) {
#pragma unroll
    for (int c = 0; c < 2; ++c) {
      int col = cbase + 16 * c + lm;
      float bc = c ? bcol1 : bcol0;
#pragma unroll
      for (int g = 0; g < 4; ++g) {
        int row = r0 + 16 * t + lq * 4 + g;
        if (row < N) {
          float v = acc[t][c][g] + bc;
          hb[(size_t)row * F + col] = f2bf(v);
          if (c) { bsum1 += v; bsq1 += v * v; }
          else   { bsum0 += v; bsq0 += v * v; }
        }
      }
    }
  }
  bsum0 += __shfl_xor(bsum0, 16); bsum0 += __shfl_xor(bsum0, 32);
  bsq0  += __shfl_xor(bsq0, 16);  bsq0  += __shfl_xor(bsq0, 32);
  bsum1 += __shfl_xor(bsum1, 16); bsum1 += __shfl_xor(bsum1, 32);
  bsq1  += __shfl_xor(bsq1, 16);  bsq1  += __shfl_xor(bsq1, 32);
  if (lq == 0) {
    float* pb = pbuf + (size_t)blockIdx.x * 256;
    pb[cbase + lm]            = bsum0;
    pb[128 + cbase + lm]      = bsq0;
    pb[cbase + 16 + lm]       = bsum1;
    pb[128 + cbase + 16 + lm] = bsq1;
  }
}

// -------- BN stats: grid-8 reduce of pbuf + ticketed last-block finalize --------
// stats = float[256] sums/sumsqs, followed by an int ticket (stats[256]).
__global__ __launch_bounds__(256) void k_bnstats(const float* __restrict__ pbuf,
                                                 const float* __restrict__ g,
                                                 const float* __restrict__ be,
                                                 float* __restrict__ stats,
                                                 float* __restrict__ scale,
                                                 float* __restrict__ shift,
                                                 float invN, int nb) {
  int t = threadIdx.x;
  float s = 0.f;
  for (int b = blockIdx.x; b < nb; b += 8) s += pbuf[(size_t)b * 256 + t];
  atomicAdd(&stats[t], s);
  __threadfence();
  __syncthreads();
  __shared__ int lastS;
  if (t == 0) {
    int ticket = atomicAdd((int*)(stats + 256), 1);
    lastS = (ticket == 7);
  }
  __syncthreads();
  if (lastS) {
    __threadfence();
    if (t < 128) {
      float sum = __hip_atomic_load(&stats[t], __ATOMIC_RELAXED, __HIP_MEMORY_SCOPE_AGENT);
      float sq  = __hip_atomic_load(&stats[t + 128], __ATOMIC_RELAXED, __HIP_MEMORY_SCOPE_AGENT);
      float mu = sum * invN;
      float var = fmaxf(sq * invN - mu * mu, 0.0f);
      float sc = g[t] * rsqrtf(var + 1e-5f);
      scale[t] = sc;
      shift[t] = be[t] - mu * sc;
    }
  }
}

// -------- BN apply + ReLU: bf16 h -> bf16 dst (8 elems/thread) --------
__global__ __launch_bounds__(256) void k_bnrelu(const unsigned short* __restrict__ h,
                                                unsigned short* __restrict__ dst,
                                                const float* __restrict__ scale,
                                                const float* __restrict__ shift, int n8) {
  int i = blockIdx.x * 256 + threadIdx.x;
  if (i >= n8) return;
  uint4 u = ((const uint4*)h)[i];
  int g = i & 15;
  float4 sc0 = ((const float4*)scale)[2 * g];
  float4 sc1 = ((const float4*)scale)[2 * g + 1];
  float4 sh0 = ((const float4*)shift)[2 * g];
  float4 sh1 = ((const float4*)shift)[2 * g + 1];
  unsigned o0 = pack2(fmaxf(fmaf(bf_lo(u.x), sc0.x, sh0.x), 0.f),
                      fmaxf(fmaf(bf_hi(u.x), sc0.y, sh0.y), 0.f));
  unsigned o1 = pack2(fmaxf(fmaf(bf_lo(u.y), sc0.z, sh0.z), 0.f),
                      fmaxf(fmaf(bf_hi(u.y), sc0.w, sh0.w), 0.f));
  unsigned o2 = pack2(fmaxf(fmaf(bf_lo(u.z), sc1.x, sh1.x), 0.f),
                      fmaxf(fmaf(bf_hi(u.z), sc1.y, sh1.y), 0.f));
  unsigned o3 = pack2(fmaxf(fmaf(bf_lo(u.w), sc1.z, sh1.z), 0.f),
                      fmaxf(fmaf(bf_hi(u.w), sc1.w, sh1.w), 0.f));
  ((uint4*)dst)[i] = make_uint4(o0, o1, o2, o3);
}

// -------- fused BN1 + ReLU + final linear 128->2: hb -> out --------
// 16 lanes per row (uint4 each); in-group shfl reduce; lane 0 writes 2 floats.
__global__ __launch_bounds__(256) void k_bnout(const unsigned short* __restrict__ hb,
                                               const float* __restrict__ scale,
                                               const float* __restrict__ shift,
                                               const float* __restrict__ Wout,
                                               const float* __restrict__ bout,
                                               float* __restrict__ out, int N) {
  __shared__ float W0s[F], W1s[F];
  int t = threadIdx.x;
  if (t < F) {
    W0s[t] = Wout[2 * t];
    W1s[t] = Wout[2 * t + 1];
  }
  __syncthreads();
  int r = blockIdx.x * 16 + (t >> 4);
  int ln = t & 15;
  if (r >= N) return;
  uint4 u = ((const uint4*)(hb + (size_t)r * F))[ln];
  float4 sc0 = ((const float4*)scale)[2 * ln];
  float4 sc1 = ((const float4*)scale)[2 * ln + 1];
  float4 sh0 = ((const float4*)shift)[2 * ln];
  float4 sh1 = ((const float4*)shift)[2 * ln + 1];
  float v[8];
  v[0] = fmaxf(fmaf(bf_lo(u.x), sc0.x, sh0.x), 0.f);
  v[1] = fmaxf(fmaf(bf_hi(u.x), sc0.y, sh0.y), 0.f);
  v[2] = fmaxf(fmaf(bf_lo(u.y), sc0.z, sh0.z), 0.f);
  v[3] = fmaxf(fmaf(bf_hi(u.y), sc0.w, sh0.w), 0.f);
  v[4] = fmaxf(fmaf(bf_lo(u.z), sc1.x, sh1.x), 0.f);
  v[5] = fmaxf(fmaf(bf_hi(u.z), sc1.y, sh1.y), 0.f);
  v[6] = fmaxf(fmaf(bf_lo(u.w), sc1.z, sh1.z), 0.f);
  v[7] = fmaxf(fmaf(bf_hi(u.w), sc1.w, sh1.w), 0.f);
  float a0 = 0.f, a1 = 0.f;
#pragma unroll
  for (int j = 0; j < 8; ++j) {
    a0 += v[j] * W0s[8 * ln + j];
    a1 += v[j] * W1s[8 * ln + j];
  }
#pragma unroll
  for (int off = 1; off < 16; off <<= 1) {
    a0 += __shfl_xor(a0, off);
    a1 += __shfl_xor(a1, off);
  }
  if (ln == 0) {
    out[2 * r]     = a0 + bout[0];
    out[2 * r + 1] = a1 + bout[1];
  }
}

extern "C" void kernel_launch(void* const* d_in, const int* in_sizes, int n_in,
                              void* d_out, int out_size, void* d_ws, size_t ws_size,
                              hipStream_t stream) {
  const float* x   = (const float*)d_in[0];
  const int*   eix = (const int*)d_in[1];
  const float* Wl0 = (const float*)d_in[2];
  const float* Wr0 = (const float*)d_in[3];
  const float* b0  = (const float*)d_in[4];
  const float* g0  = (const float*)d_in[5];
  const float* be0 = (const float*)d_in[6];
  const float* Wl1 = (const float*)d_in[7];
  const float* Wr1 = (const float*)d_in[8];
  const float* b1  = (const float*)d_in[9];
  const float* g1  = (const float*)d_in[10];
  const float* be1 = (const float*)d_in[11];
  const float* Wo  = (const float*)d_in[12];
  const float* bo  = (const float*)d_in[13];

  int N = in_sizes[0] / F;     // 50000
  int E = in_sizes[1] / 2;     // 600000
  const int* src  = eix;
  const int* dstv = eix + E;

  int nRowBlocks = (N + 63) / 64;         // 782
  size_t Npad = (size_t)nRowBlocks * 64;  // 50048
  int nScanB = (N + 1023) / 1024;         // 49

  // ws layout: aggb | xb | hb (bf16 Npad*F) | WcatT0 | WcatT1 | scale | shift |
  //            A[N] | bsum[64] | stats0[257] | stats1[257] | adj[E] | pbuf
  unsigned short* aggb   = (unsigned short*)d_ws;
  unsigned short* xb     = aggb + Npad * F;
  unsigned short* hb     = xb + Npad * F;
  unsigned short* WcatT0 = hb + Npad * F;
  unsigned short* WcatT1 = WcatT0 + 256 * F;
  float* scale  = (float*)(WcatT1 + 256 * F);
  float* shift  = scale + F;
  int*   A      = (int*)(shift + F);
  int*   bsum   = A + N;
  float* stats0 = (float*)(bsum + 64);   // 256 f + 1 int ticket
  float* stats1 = stats0 + 257;
  int*   adj    = (int*)(stats1 + 257);
  float* pbuf   = (float*)(adj + E);     // [nRowBlocks][256]

  // zero A + bsum + stats0 + stats1 in one contiguous memset
  hipMemsetAsync(A, 0, (size_t)(N + 64 + 514) * sizeof(int), stream);

  // ---- CSR build (shared by both layers) ----
  k_count<<<(E + 255) / 256, 256, 0, stream>>>(dstv, A, E);
  k_scanA<<<nScanB, 1024, 0, stream>>>(A, bsum, N);
  k_scanC<<<nScanB, 1024, 0, stream>>>(A, bsum, N, nScanB);
  k_fill<<<(E + 255) / 256, 256, 0, stream>>>(src, dstv, A, adj, E);

  // ---- merged prep: x conversion + both weight transposes ----
  int n4 = N * F / 4, n8 = N * F / 8;
  k_prep<<<(n4 + 2 * 256 * F + 255) / 256, 256, 0, stream>>>(x, Wl0, Wr0, Wl1, Wr1,
                                                             xb, WcatT0, WcatT1, n4);

  // ---- layer 0 ----
  k_gather<<<(N + 3) / 4, 256, 0, stream>>>(xb, A, adj, aggb, N);
  k_gemm<<<nRowBlocks, 256, 0, stream>>>(aggb, xb, WcatT0, b0, hb, pbuf, N);
  k_bnstats<<<8, 256, 0, stream>>>(pbuf, g0, be0, stats0, scale, shift, 1.0f / N, nRowBlocks);
  k_bnrelu<<<(n8 + 255) / 256, 256, 0, stream>>>(hb, xb, scale, shift, n8);  // -> xb

  // ---- layer 1 ----
  k_gather<<<(N + 3) / 4, 256, 0, stream>>>(xb, A, adj, aggb, N);
  k_gemm<<<nRowBlocks, 256, 0, stream>>>(aggb, xb, WcatT1, b1, hb, pbuf, N);
  k_bnstats<<<8, 256, 0, stream>>>(pbuf, g1, be1, stats1, scale, shift, 1.0f / N, nRowBlocks);

  // ---- fused BN1 + ReLU + output head ----
  k_bnout<<<(N + 15) / 16, 256, 0, stream>>>(hb, scale, shift, Wo, bo, (float*)d_out, N);
}